// Round 7
// baseline (152.107 us; speedup 1.0000x reference)
//
#include <hip/hip_runtime.h>

// Sinkhorn top-k, sorted-value domain, x <- 1/(Mx), 200 apps.
// R7: barrier-free, LDS-free iteration. One wave64 per batch, 8 rows/lane,
// x (fp16) in 4 VGPRs/lane. The +-16 window of lane l's rows is exactly the
// x of lanes l-2..l+2 -> fetched with 16 v_mov_dpp (wave_shr1/shl1 chained),
// bound_ctrl zero-fill = band truncation at the wave edges. Per app:
// 16 DPP + 160 fdot2 + 8 rcp, zero lgkmcnt, zero s_barrier.

#define N      512
#define BATCH  16
#define KTOP   50
#define NAPPS  200         // 100 iterations x (col + row) - exact iterate count
#define COEF   1442.6950408889634f   // log2(e) / EPSILON, EPSILON = 1e-3

typedef _Float16 h2 __attribute__((ext_vector_type(2)));

static __device__ __forceinline__ h2 pack2(float a, float b) {
    return __builtin_bit_cast(h2, __builtin_amdgcn_cvt_pkrtz(a, b));
}
// lane i <- lane i-1 (zero into lane 0)
static __device__ __forceinline__ unsigned shr1(unsigned v) {
    return (unsigned)__builtin_amdgcn_update_dpp(0, (int)v, 0x138, 0xF, 0xF, true);
}
// lane i <- lane i+1 (zero into lane 63)
static __device__ __forceinline__ unsigned shl1(unsigned v) {
    return (unsigned)__builtin_amdgcn_update_dpp(0, (int)v, 0x130, 0xF, 0xF, true);
}

__global__ __launch_bounds__(64, 1)
void sinkhorn_topk_kernel(const float* __restrict__ scores,
                          float* __restrict__ out) {
    __shared__ __align__(16) float tv[N];   // sorted values, descending
    __shared__ int                 ti[N];   // original index of each rank

    const int lane = threadIdx.x;           // 0..63
    const int b    = blockIdx.x;

    ((float4*)tv)[2 * lane]     = ((const float4*)(scores + b * N))[2 * lane];
    ((float4*)tv)[2 * lane + 1] = ((const float4*)(scores + b * N))[2 * lane + 1];
#pragma unroll
    for (int r = 0; r < 8; ++r) ti[8 * lane + r] = 8 * lane + r;
    __syncthreads();

    // ---- bitonic sort, descending; 64 lanes x 4 compare-exchanges/step ----
    for (int k = 2; k <= N; k <<= 1) {
        for (int j = k >> 1; j > 0; j >>= 1) {
#pragma unroll
            for (int e = 0; e < 4; ++e) {
                int q = lane + e * 64;                 // pair id 0..255
                int i = ((q & ~(j - 1)) << 1) | (q & (j - 1));
                int p = i | j;
                float va = tv[i], vb = tv[p];
                bool up = ((i & k) == 0);
                bool sw = up ? (va < vb) : (va > vb);
                if (sw) {
                    tv[i] = vb; tv[p] = va;
                    int t_ = ti[i]; ti[i] = ti[p]; ti[p] = t_;
                }
            }
            __syncthreads();
        }
    }

    // ---- K band: rows 8l..8l+7, cols 8l-16..8l+23 (5 lanes' blocks) ----
    const int r0    = 8 * lane;
    const int gbase = r0 - 16;
    float trow[8];
#pragma unroll
    for (int r = 0; r < 8; ++r) trow[r] = tv[r0 + r];

    h2 K2[8][20];
#pragma unroll
    for (int m = 0; m < 20; ++m) {
        int g0 = gbase + 2 * m, g1 = g0 + 1;
        int c0 = min(max(g0, 0), N - 1), c1 = min(max(g1, 0), N - 1);
        float s0 = tv[c0], s1 = tv[c1];
#pragma unroll
        for (int r = 0; r < 8; ++r) {
            float d0 = trow[r] - s0, d1 = trow[r] - s1;
            K2[r][m] = pack2(exp2f(-COEF * d0 * d0), exp2f(-COEF * d1 * d1));
        }
    }

    // ---- iterate in registers: x fp16, 8 rows/lane = 4 dwords ----
    unsigned x[4] = {0x3C003C00u, 0x3C003C00u, 0x3C003C00u, 0x3C003C00u};
    unsigned w[20];                          // 40-half window, dwords

    for (int t = 0; t < NAPPS; ++t) {
#pragma unroll
        for (int k = 0; k < 4; ++k) {
            w[8 + k]  = x[k];                // own block (cols 8l..8l+7)
            w[4 + k]  = shr1(x[k]);          // lane l-1
            w[12 + k] = shl1(x[k]);          // lane l+1
        }
#pragma unroll
        for (int k = 0; k < 4; ++k) {
            w[k]      = shr1(w[4 + k]);      // lane l-2
            w[16 + k] = shl1(w[12 + k]);     // lane l+2
        }
        float acc[8] = {0.f, 0.f, 0.f, 0.f, 0.f, 0.f, 0.f, 0.f};
#pragma unroll
        for (int m = 0; m < 20; ++m) {
            h2 wm = __builtin_bit_cast(h2, w[m]);
#pragma unroll
            for (int r = 0; r < 8; ++r)
                acc[r] = __builtin_amdgcn_fdot2(K2[r][m], wm, acc[r], false);
        }
#pragma unroll
        for (int k = 0; k < 4; ++k)
            x[k] = __builtin_bit_cast(unsigned,
                     pack2(__builtin_amdgcn_rcpf(acc[2 * k]),
                           __builtin_amdgcn_rcpf(acc[2 * k + 1])));
    }
    // x = r (app 200); w = window of c (app 199)

    // ---- epilogue: out_row = r_a * sum_{gc<K} K[a][gc] c_gc ----
    float accK[8] = {0.f, 0.f, 0.f, 0.f, 0.f, 0.f, 0.f, 0.f};
#pragma unroll
    for (int m = 0; m < 20; ++m) {
        int g0 = gbase + 2 * m;
        int g1 = g0 + 1;
        h2 cw = __builtin_bit_cast(h2, w[m]);
        float c0 = (g0 >= 0 && g0 < KTOP) ? (float)cw[0] : 0.f;
        float c1 = (g1 >= 0 && g1 < KTOP) ? (float)cw[1] : 0.f;
        h2 cm = pack2(c0, c1);
#pragma unroll
        for (int r = 0; r < 8; ++r)
            accK[r] = __builtin_amdgcn_fdot2(K2[r][m], cm, accK[r], false);
    }
#pragma unroll
    for (int k = 0; k < 4; ++k) {
        h2 xr = __builtin_bit_cast(h2, x[k]);
        out[b * N + ti[r0 + 2 * k]]     = (float)xr[0] * accK[2 * k];
        out[b * N + ti[r0 + 2 * k + 1]] = (float)xr[1] * accK[2 * k + 1];
    }
}

extern "C" void kernel_launch(void* const* d_in, const int* in_sizes, int n_in,
                              void* d_out, int out_size, void* d_ws, size_t ws_size,
                              hipStream_t stream) {
    const float* scores = (const float*)d_in[0];
    float* out = (float*)d_out;
    sinkhorn_topk_kernel<<<dim3(BATCH), dim3(64), 0, stream>>>(scores, out);
}